// Round 6
// baseline (417.560 us; speedup 1.0000x reference)
//
#include <hip/hip_runtime.h>

#define TT 16384
#define DD 4096
#define OO 4096
#define NE 8
#define RRK 64
#define KSPLIT 4
#define KCHUNK 1024

typedef _Float16 f16x8 __attribute__((ext_vector_type(8)));
typedef _Float16 f16x4 __attribute__((ext_vector_type(4)));
typedef float f32x4 __attribute__((ext_vector_type(4)));

// workspace layout (bytes)
#define CNT_OFF 0             // 8 ints
#define PERM_OFF 1024         // 8*TT ints = 512KB
#define AT_OFF (1u << 20)     // 8*64*4096 f16 = 4MB: A^T [e][r][k]
#define BT_OFF (5u << 20)     // 8*4096*64 f16 = 4MB: B^T [e][o][r]
#define HP_OFF (9u << 20)     // 4*TT*64 f16 = 8MB: H k-partials, unscaled

// ---------------------------------------------------------------------------
// prep: scatter tokens into per-adapter buckets; transpose+cast A and B to f16
// ---------------------------------------------------------------------------
__global__ void prep_kernel(const int* __restrict__ ids,
                            const float* __restrict__ A,
                            const float* __restrict__ B,
                            int* __restrict__ cnt,
                            int* __restrict__ perm,
                            _Float16* __restrict__ At,
                            _Float16* __restrict__ Bt) {
  const int bid = blockIdx.x, tid = threadIdx.x;
  if (bid < 64) {                      // scatter
    int t = bid * 256 + tid;
    int e = ids[t];
    int pos = atomicAdd(&cnt[e], 1);
    perm[e * TT + pos] = t;
    return;
  }
  __shared__ float tile[64][65];
  if (bid < 576) {                     // A[e][k][r] -> At[e][r][k]
    int idx = bid - 64;
    int e = idx >> 6, kb = (idx & 63) << 6;
    #pragma unroll
    for (int i = 0; i < 16; ++i) {
      int lin = i * 256 + tid;
      int kr = lin >> 6, r = lin & 63;
      tile[kr][r] = A[((size_t)e * DD + kb + kr) * RRK + r];
    }
    __syncthreads();
    #pragma unroll
    for (int i = 0; i < 16; ++i) {
      int lin = i * 256 + tid;
      int r = lin >> 6, kk = lin & 63;
      At[((size_t)e * RRK + r) * DD + kb + kk] = (_Float16)tile[kk][r];
    }
  } else {                             // B[e][r][o] -> Bt[e][o][r]
    int idx = bid - 576;
    int e = idx >> 6, ob = (idx & 63) << 6;
    #pragma unroll
    for (int i = 0; i < 16; ++i) {
      int lin = i * 256 + tid;
      int r = lin >> 6, o = lin & 63;
      tile[r][o] = B[((size_t)e * RRK + r) * OO + ob + o];
    }
    __syncthreads();
    #pragma unroll
    for (int i = 0; i < 16; ++i) {
      int lin = i * 256 + tid;
      int o = lin >> 6, r2 = lin & 63;
      Bt[((size_t)e * OO + ob + o) * RRK + r2] = (_Float16)tile[r2][o];
    }
  }
}

// ---------------------------------------------------------------------------
// stage 1: HP[s][t][:] = x[t][ks..] @ A[e][ks..]   (k-split by 4, unscaled)
// LDS-staged, coalesced. 64 tok x 64 R x 1024K per block. (R2-proven)
// ---------------------------------------------------------------------------
__global__ __launch_bounds__(256, 2)
void lora_stage1(const float* __restrict__ x,
                 const _Float16* __restrict__ At,
                 const int* __restrict__ cnt,
                 const int* __restrict__ perm,
                 _Float16* __restrict__ HP) {
  __shared__ _Float16 Xs[64][72];
  __shared__ _Float16 As[64][72];
  __shared__ int toks[64];
  const int tid = threadIdx.x;
  const int lane = tid & 63, w = tid >> 6;

  int tiles = 0;
  #pragma unroll
  for (int ee = 0; ee < NE; ++ee) tiles += (cnt[ee] + 63) >> 6;

  for (int wi = blockIdx.x; wi < tiles * KSPLIT; wi += gridDim.x) {
    int tile = wi >> 2, s = wi & 3;
    int e = 0, base = 0, n_e = 0;
    {
      int acc0 = 0;
      #pragma unroll
      for (int ee = 0; ee < NE; ++ee) {
        int c = cnt[ee];
        int tl = (c + 63) >> 6;
        if (tile >= acc0 && tile < acc0 + tl) { e = ee; base = acc0; n_e = c; }
        acc0 += tl;
      }
    }
    int m0 = (tile - base) << 6;
    int kbase = s * KCHUNK;

    if (tid < 64) {
      int rloc = m0 + tid;
      toks[tid] = (rloc < n_e) ? perm[e * TT + rloc] : -1;
    }
    __syncthreads();

    const int srow = tid >> 2;
    const int seg = (tid & 3) << 4;
    int tk0 = toks[srow];
    if (tk0 < 0) tk0 = toks[0];
    const float* xp = x + (size_t)tk0 * DD + seg;
    const _Float16* ap = At + ((size_t)e * RRK + srow) * DD + seg;

    f32x4 acc[4] = {};

    for (int k0 = kbase; k0 < kbase + KCHUNK; k0 += 64) {
      float4 v0 = *(const float4*)(xp + k0);
      float4 v1 = *(const float4*)(xp + k0 + 4);
      float4 v2 = *(const float4*)(xp + k0 + 8);
      float4 v3 = *(const float4*)(xp + k0 + 12);
      f16x8 xa, xb;
      xa[0] = (_Float16)v0.x; xa[1] = (_Float16)v0.y;
      xa[2] = (_Float16)v0.z; xa[3] = (_Float16)v0.w;
      xa[4] = (_Float16)v1.x; xa[5] = (_Float16)v1.y;
      xa[6] = (_Float16)v1.z; xa[7] = (_Float16)v1.w;
      xb[0] = (_Float16)v2.x; xb[1] = (_Float16)v2.y;
      xb[2] = (_Float16)v2.z; xb[3] = (_Float16)v2.w;
      xb[4] = (_Float16)v3.x; xb[5] = (_Float16)v3.y;
      xb[6] = (_Float16)v3.z; xb[7] = (_Float16)v3.w;
      *(f16x8*)&Xs[srow][seg] = xa;
      *(f16x8*)&Xs[srow][seg + 8] = xb;
      *(f16x8*)&As[srow][seg] = *(const f16x8*)(ap + k0);
      *(f16x8*)&As[srow][seg + 8] = *(const f16x8*)(ap + k0 + 8);
      __syncthreads();

      const int mr = w * 16 + (lane & 15);
      const int kq = (lane >> 4) << 3;
      #pragma unroll
      for (int ks = 0; ks < 2; ++ks) {
        f16x8 af = *(const f16x8*)&Xs[mr][ks * 32 + kq];
        #pragma unroll
        for (int nf = 0; nf < 4; ++nf) {
          f16x8 bfr = *(const f16x8*)&As[nf * 16 + (lane & 15)][ks * 32 + kq];
          acc[nf] = __builtin_amdgcn_mfma_f32_16x16x32_f16(af, bfr, acc[nf], 0, 0, 0);
        }
      }
      __syncthreads();
    }

    // partial epilogue (unscaled, f16)
    const int rq = (lane >> 4) << 2;
    #pragma unroll
    for (int rg = 0; rg < 4; ++rg) {
      int tk = toks[w * 16 + rq + rg];
      if (tk >= 0) {
        _Float16* hp = HP + ((size_t)s * TT + tk) * RRK + (lane & 15);
        #pragma unroll
        for (int nf = 0; nf < 4; ++nf) {
          hp[nf * 16] = (_Float16)acc[nf][rg];
        }
      }
    }
    __syncthreads();
  }
}

// ---------------------------------------------------------------------------
// stage 2: out[t][:] = base[t][:] + H[t] @ B[e]
// Block = 64-token tile x 1024 cols (8 halves of 128). Swapped-operand MFMA,
// then wave-private XOR-swizzled LDS transpose so each row's base/out access
// is a 512B-contiguous float2-per-lane instruction (long DRAM bursts).
// H-fragment load folds the 4-way k-partial reduction + scaling.
// One __syncthreads per work item (toks staging); transpose is barrier-free.
// ---------------------------------------------------------------------------
__global__ __launch_bounds__(256, 4)
void lora_stage2(const float* __restrict__ baseo,
                 const _Float16* __restrict__ Bt,
                 const _Float16* __restrict__ HP,
                 const float* __restrict__ scaling,
                 const int* __restrict__ cnt,
                 const int* __restrict__ perm,
                 float* __restrict__ out) {
  __shared__ int toks[64];
  __shared__ f32x4 ldsT[2048];        // 4 waves x 16 rows x 32 slots(16B)
  const int tid = threadIdx.x;
  const int lane = tid & 63, w = tid >> 6;
  const int lr = lane & 15, g = lane >> 4;
  const int kq = g << 3;

  int tiles = 0;
  #pragma unroll
  for (int ee = 0; ee < NE; ++ee) tiles += (cnt[ee] + 63) >> 6;
  int tot = tiles << 2;

  for (int wi = blockIdx.x; wi < tot; wi += gridDim.x) {
    int tile = wi >> 2, pg = wi & 3;
    int e = 0, m0 = 0, n_e = 0;
    {
      int acc0 = 0;
      #pragma unroll
      for (int ee = 0; ee < NE; ++ee) {
        int c = cnt[ee];
        int tl = (c + 63) >> 6;
        if (tile >= acc0 && tile < acc0 + tl) { e = ee; m0 = (tile - acc0) << 6; n_e = c; }
        acc0 += tl;
      }
    }
    if (tid < 64) {
      int rloc = m0 + tid;
      toks[tid] = (rloc < n_e) ? perm[e * TT + rloc] : -1;
    }
    __syncthreads();

    // per-lane H fragment: fold 4 k-partials (f32) + scaling -> f16
    float s_e = scaling[e];
    int tokA = toks[w * 16 + lr];
    if (tokA < 0) tokA = toks[0];
    f16x8 hf0, hf1;
    {
      float sum[16];
      #pragma unroll
      for (int i = 0; i < 16; ++i) sum[i] = 0.f;
      #pragma unroll
      for (int sp = 0; sp < KSPLIT; ++sp) {
        const f16x8* hp = (const f16x8*)(HP + ((size_t)sp * TT + tokA) * RRK + kq);
        f16x8 h0 = hp[0];           // k = kq..kq+7
        f16x8 h1 = hp[4];           // k = kq+32..kq+39
        #pragma unroll
        for (int i = 0; i < 8; ++i) { sum[i] += (float)h0[i]; sum[8 + i] += (float)h1[i]; }
      }
      #pragma unroll
      for (int i = 0; i < 8; ++i) {
        hf0[i] = (_Float16)(sum[i] * s_e);
        hf1[i] = (_Float16)(sum[8 + i] * s_e);
      }
    }

    const _Float16* bbase = Bt + (size_t)e * OO * RRK;

    for (int ph = 0; ph < 8; ++ph) {
      int colh = (pg << 10) + (ph << 7);
      const _Float16* bp = bbase + (size_t)(colh + lr) * RRK + kq;

      f32x4 acc[8];
      #pragma unroll
      for (int of = 0; of < 8; ++of) acc[of] = (f32x4){0.f, 0.f, 0.f, 0.f};
      #pragma unroll
      for (int of = 0; of < 8; ++of) {
        f16x8 b0 = *(const f16x8*)(bp + (size_t)of * 16 * RRK);
        f16x8 b1 = *(const f16x8*)(bp + (size_t)of * 16 * RRK + 32);
        acc[of] = __builtin_amdgcn_mfma_f32_16x16x32_f16(b0, hf0, acc[of], 0, 0, 0);
        acc[of] = __builtin_amdgcn_mfma_f32_16x16x32_f16(b1, hf1, acc[of], 0, 0, 0);
      }

      // wave-private transpose: lane holds row lr, col-quad cq = of*4+g
      #pragma unroll
      for (int of = 0; of < 8; ++of) {
        int cq = (of << 2) + g;
        ldsT[(w << 9) + (lr << 5) + (cq ^ (lr & 7))] = acc[of];
      }
      asm volatile("s_waitcnt lgkmcnt(0)" ::: "memory");
      __builtin_amdgcn_sched_barrier(0);

      // row-sequential epilogue: 512B contiguous per instruction
      #pragma unroll
      for (int j = 0; j < 16; ++j) {
        int row = m0 + (w << 4) + j;
        if (row < n_e) {                    // wave-uniform
          int tkj = toks[(w << 4) + j];
          int slot = (lane >> 1) ^ (j & 7);
          const float2* lp = (const float2*)(ldsT + (w << 9) + (j << 5) + slot);
          float2 v = lp[lane & 1];
          size_t off = (size_t)tkj * OO + colh + (lane << 1);
          float2 b2 = *(const float2*)(baseo + off);
          float2 r2;
          r2.x = b2.x + v.x;
          r2.y = b2.y + v.y;
          *(float2*)(out + off) = r2;
        }
      }
      __builtin_amdgcn_sched_barrier(0);    // keep next ph's ds_writes below reads
    }
    __syncthreads();                        // protect toks before next wi
  }
}

extern "C" void kernel_launch(void* const* d_in, const int* in_sizes, int n_in,
                              void* d_out, int out_size, void* d_ws, size_t ws_size,
                              hipStream_t stream) {
  const float* x = (const float*)d_in[0];
  const float* baseo = (const float*)d_in[1];
  const float* A = (const float*)d_in[2];
  const float* B = (const float*)d_in[3];
  const float* scaling = (const float*)d_in[4];
  const int* ids = (const int*)d_in[5];
  float* out = (float*)d_out;
  char* ws = (char*)d_ws;

  int* cnt = (int*)(ws + CNT_OFF);
  int* perm = (int*)(ws + PERM_OFF);
  _Float16* At = (_Float16*)(ws + AT_OFF);
  _Float16* Bt = (_Float16*)(ws + BT_OFF);
  _Float16* HP = (_Float16*)(ws + HP_OFF);

  hipMemsetAsync(cnt, 0, NE * sizeof(int), stream);
  hipLaunchKernelGGL(prep_kernel, dim3(1088), dim3(256), 0, stream,
                     ids, A, B, cnt, perm, At, Bt);
  hipLaunchKernelGGL(lora_stage1, dim3(1056), dim3(256), 0, stream,
                     x, At, cnt, perm, HP);
  hipLaunchKernelGGL(lora_stage2, dim3(1024), dim3(256), 0, stream,
                     baseo, Bt, HP, scaling, cnt, perm, out);
}

// Round 7
// 404.455 us; speedup vs baseline: 1.0324x; 1.0324x over previous
//
#include <hip/hip_runtime.h>

#define TT 16384
#define DD 4096
#define OO 4096
#define NE 8
#define RRK 64
#define KSPLIT 8
#define KCHUNK 512

typedef _Float16 f16x8 __attribute__((ext_vector_type(8)));
typedef _Float16 f16x4 __attribute__((ext_vector_type(4)));
typedef float f32x4 __attribute__((ext_vector_type(4)));

// workspace layout (bytes)
#define CNT_OFF 0             // 8 ints
#define PERM_OFF 1024         // 8*TT ints = 512KB
#define AT_OFF (1u << 20)     // 8*64*4096 f16 = 4MB: A^T [e][r][k]
#define BT_OFF (5u << 20)     // 8*4096*64 f16 = 4MB: B^T [e][o][r]
#define HP_OFF (9u << 20)     // 8*TT*64 f16 = 16MB: H k-partials, unscaled

// ---------------------------------------------------------------------------
// prep: scatter tokens into per-adapter buckets; transpose+cast A and B to f16
// ---------------------------------------------------------------------------
__global__ void prep_kernel(const int* __restrict__ ids,
                            const float* __restrict__ A,
                            const float* __restrict__ B,
                            int* __restrict__ cnt,
                            int* __restrict__ perm,
                            _Float16* __restrict__ At,
                            _Float16* __restrict__ Bt) {
  const int bid = blockIdx.x, tid = threadIdx.x;
  if (bid < 64) {                      // scatter
    int t = bid * 256 + tid;
    int e = ids[t];
    int pos = atomicAdd(&cnt[e], 1);
    perm[e * TT + pos] = t;
    return;
  }
  __shared__ float tile[64][65];
  if (bid < 576) {                     // A[e][k][r] -> At[e][r][k]
    int idx = bid - 64;
    int e = idx >> 6, kb = (idx & 63) << 6;
    #pragma unroll
    for (int i = 0; i < 16; ++i) {
      int lin = i * 256 + tid;
      int kr = lin >> 6, r = lin & 63;
      tile[kr][r] = A[((size_t)e * DD + kb + kr) * RRK + r];
    }
    __syncthreads();
    #pragma unroll
    for (int i = 0; i < 16; ++i) {
      int lin = i * 256 + tid;
      int r = lin >> 6, kk = lin & 63;
      At[((size_t)e * RRK + r) * DD + kb + kk] = (_Float16)tile[kk][r];
    }
  } else {                             // B[e][r][o] -> Bt[e][o][r]
    int idx = bid - 576;
    int e = idx >> 6, ob = (idx & 63) << 6;
    #pragma unroll
    for (int i = 0; i < 16; ++i) {
      int lin = i * 256 + tid;
      int r = lin >> 6, o = lin & 63;
      tile[r][o] = B[((size_t)e * RRK + r) * OO + ob + o];
    }
    __syncthreads();
    #pragma unroll
    for (int i = 0; i < 16; ++i) {
      int lin = i * 256 + tid;
      int o = lin >> 6, r2 = lin & 63;
      Bt[((size_t)e * OO + ob + o) * RRK + r2] = (_Float16)tile[r2][o];
    }
  }
}

// ---------------------------------------------------------------------------
// stage 1: HP[s][t][:] = x[t][ks..] @ A[e][ks..]   (k-split by 8, unscaled)
// LDS-staged, coalesced (R2-proven structure); 4 blocks/CU for barrier overlap.
// ---------------------------------------------------------------------------
__global__ __launch_bounds__(256, 4)
void lora_stage1(const float* __restrict__ x,
                 const _Float16* __restrict__ At,
                 const int* __restrict__ cnt,
                 const int* __restrict__ perm,
                 _Float16* __restrict__ HP) {
  __shared__ _Float16 Xs[64][72];
  __shared__ _Float16 As[64][72];
  __shared__ int toks[64];
  const int tid = threadIdx.x;
  const int lane = tid & 63, w = tid >> 6;

  int tiles = 0;
  #pragma unroll
  for (int ee = 0; ee < NE; ++ee) tiles += (cnt[ee] + 63) >> 6;

  for (int wi = blockIdx.x; wi < tiles * KSPLIT; wi += gridDim.x) {
    int tile = wi >> 3, s = wi & 7;
    int e = 0, base = 0, n_e = 0;
    {
      int acc0 = 0;
      #pragma unroll
      for (int ee = 0; ee < NE; ++ee) {
        int c = cnt[ee];
        int tl = (c + 63) >> 6;
        if (tile >= acc0 && tile < acc0 + tl) { e = ee; base = acc0; n_e = c; }
        acc0 += tl;
      }
    }
    int m0 = (tile - base) << 6;
    int kbase = s * KCHUNK;

    if (tid < 64) {
      int rloc = m0 + tid;
      toks[tid] = (rloc < n_e) ? perm[e * TT + rloc] : -1;
    }
    __syncthreads();

    const int srow = tid >> 2;
    const int seg = (tid & 3) << 4;
    int tk0 = toks[srow];
    if (tk0 < 0) tk0 = toks[0];
    const float* xp = x + (size_t)tk0 * DD + seg;
    const _Float16* ap = At + ((size_t)e * RRK + srow) * DD + seg;

    f32x4 acc[4] = {};

    for (int k0 = kbase; k0 < kbase + KCHUNK; k0 += 64) {
      float4 v0 = *(const float4*)(xp + k0);
      float4 v1 = *(const float4*)(xp + k0 + 4);
      float4 v2 = *(const float4*)(xp + k0 + 8);
      float4 v3 = *(const float4*)(xp + k0 + 12);
      f16x8 xa, xb;
      xa[0] = (_Float16)v0.x; xa[1] = (_Float16)v0.y;
      xa[2] = (_Float16)v0.z; xa[3] = (_Float16)v0.w;
      xa[4] = (_Float16)v1.x; xa[5] = (_Float16)v1.y;
      xa[6] = (_Float16)v1.z; xa[7] = (_Float16)v1.w;
      xb[0] = (_Float16)v2.x; xb[1] = (_Float16)v2.y;
      xb[2] = (_Float16)v2.z; xb[3] = (_Float16)v2.w;
      xb[4] = (_Float16)v3.x; xb[5] = (_Float16)v3.y;
      xb[6] = (_Float16)v3.z; xb[7] = (_Float16)v3.w;
      *(f16x8*)&Xs[srow][seg] = xa;
      *(f16x8*)&Xs[srow][seg + 8] = xb;
      *(f16x8*)&As[srow][seg] = *(const f16x8*)(ap + k0);
      *(f16x8*)&As[srow][seg + 8] = *(const f16x8*)(ap + k0 + 8);
      __syncthreads();

      const int mr = w * 16 + (lane & 15);
      const int kq = (lane >> 4) << 3;
      #pragma unroll
      for (int ks = 0; ks < 2; ++ks) {
        f16x8 af = *(const f16x8*)&Xs[mr][ks * 32 + kq];
        #pragma unroll
        for (int nf = 0; nf < 4; ++nf) {
          f16x8 bfr = *(const f16x8*)&As[nf * 16 + (lane & 15)][ks * 32 + kq];
          acc[nf] = __builtin_amdgcn_mfma_f32_16x16x32_f16(af, bfr, acc[nf], 0, 0, 0);
        }
      }
      __syncthreads();
    }

    // partial epilogue (unscaled, f16)
    const int rq = (lane >> 4) << 2;
    #pragma unroll
    for (int rg = 0; rg < 4; ++rg) {
      int tk = toks[w * 16 + rq + rg];
      if (tk >= 0) {
        _Float16* hp = HP + ((size_t)s * TT + tk) * RRK + (lane & 15);
        #pragma unroll
        for (int nf = 0; nf < 4; ++nf) {
          hp[nf * 16] = (_Float16)acc[nf][rg];
        }
      }
    }
    __syncthreads();
  }
}

// ---------------------------------------------------------------------------
// stage 2: out[t][:] = base[t][:] + H[t] @ B[e]   (R3 structure + occupancy)
// LDS-free, barrier-free, VGPR~64, up to 6 blocks/CU. 64 tok x 256 col tiles.
// Bijective XCD swizzle: the ~32 consecutive work items sharing one Bt panel
// run on the same XCD's L2. H-fragment load folds k-partials + scaling.
// D = B^T(A-op) x H^T(B-op): lane owns one token row, float4 RMW epilogue.
// ---------------------------------------------------------------------------
#define S2_GRID 4096
__global__ __launch_bounds__(256, 6)
void lora_stage2(const float* __restrict__ baseo,
                 const _Float16* __restrict__ Bt,
                 const _Float16* __restrict__ HP,
                 const float* __restrict__ scaling,
                 const int* __restrict__ cnt,
                 const int* __restrict__ perm,
                 float* __restrict__ out) {
  const int tid = threadIdx.x;
  const int lane = tid & 63, w = tid >> 6;
  const int lr = lane & 15;
  const int g = lane >> 4;
  const int kq = g << 3;
  const int g4 = g << 2;

  int tot = 0;
  #pragma unroll
  for (int ee = 0; ee < NE; ++ee) tot += ((cnt[ee] + 63) >> 6) << 4;

  // XCD-aware swizzle (grid 4096 = 8 * 512): consecutive work items -> same XCD
  int bs = ((blockIdx.x & 7) << 9) | (blockIdx.x >> 3);

  for (int wi = bs; wi < tot; wi += S2_GRID) {
    int e = 0, base = 0, n_e = 0;
    {
      int acc0 = 0;
      #pragma unroll
      for (int ee = 0; ee < NE; ++ee) {
        int c = cnt[ee];
        int work = ((c + 63) >> 6) << 4;
        if (wi >= acc0 && wi < acc0 + work) { e = ee; base = acc0; n_e = c; }
        acc0 += work;
      }
    }
    int local = wi - base;
    int tiles_m = (n_e + 63) >> 6;
    int mt = local % tiles_m;           // M fastest: consecutive wi share Bt panel
    int nt = local / tiles_m;
    int m0 = mt << 6, o0 = nt << 8;

    int row = m0 + w * 16 + lr;
    bool valid = row < n_e;
    int tk = perm[e * TT + (valid ? row : n_e - 1)];

    // H fragments: fold KSPLIT f16 partials (f32 sum) + scaling -> f16
    float s_e = scaling[e];
    f16x8 hf0, hf1;
    {
      float sum[16];
      #pragma unroll
      for (int i = 0; i < 16; ++i) sum[i] = 0.f;
      #pragma unroll
      for (int sp = 0; sp < KSPLIT; ++sp) {
        const f16x8* hp = (const f16x8*)(HP + ((size_t)sp * TT + tk) * RRK + kq);
        f16x8 h0 = hp[0];             // k = kq..kq+7
        f16x8 h1 = hp[4];             // k = kq+32..kq+39
        #pragma unroll
        for (int i = 0; i < 8; ++i) { sum[i] += (float)h0[i]; sum[8 + i] += (float)h1[i]; }
      }
      #pragma unroll
      for (int i = 0; i < 8; ++i) {
        hf0[i] = (_Float16)(sum[i] * s_e);
        hf1[i] = (_Float16)(sum[8 + i] * s_e);
      }
    }

    const _Float16* bp = Bt + ((size_t)e * OO + o0 + lr) * RRK + kq;

    f32x4 acc[16];
    #pragma unroll
    for (int of = 0; of < 16; ++of) acc[of] = (f32x4){0.f, 0.f, 0.f, 0.f};

    #pragma unroll
    for (int of = 0; of < 16; ++of) {
      f16x8 b0 = *(const f16x8*)(bp + (size_t)of * 16 * RRK);
      f16x8 b1 = *(const f16x8*)(bp + (size_t)of * 16 * RRK + 32);
      acc[of] = __builtin_amdgcn_mfma_f32_16x16x32_f16(b0, hf0, acc[of], 0, 0, 0);
      acc[of] = __builtin_amdgcn_mfma_f32_16x16x32_f16(b1, hf1, acc[of], 0, 0, 0);
    }

    if (valid) {
      size_t rowoff = (size_t)tk * OO + o0 + g4;
      #pragma unroll
      for (int of = 0; of < 16; ++of) {
        size_t off = rowoff + (size_t)of * 16;
        float4 b4 = *(const float4*)(baseo + off);
        float4 r4;
        r4.x = b4.x + acc[of][0];
        r4.y = b4.y + acc[of][1];
        r4.z = b4.z + acc[of][2];
        r4.w = b4.w + acc[of][3];
        *(float4*)(out + off) = r4;
      }
    }
  }
}

extern "C" void kernel_launch(void* const* d_in, const int* in_sizes, int n_in,
                              void* d_out, int out_size, void* d_ws, size_t ws_size,
                              hipStream_t stream) {
  const float* x = (const float*)d_in[0];
  const float* baseo = (const float*)d_in[1];
  const float* A = (const float*)d_in[2];
  const float* B = (const float*)d_in[3];
  const float* scaling = (const float*)d_in[4];
  const int* ids = (const int*)d_in[5];
  float* out = (float*)d_out;
  char* ws = (char*)d_ws;

  int* cnt = (int*)(ws + CNT_OFF);
  int* perm = (int*)(ws + PERM_OFF);
  _Float16* At = (_Float16*)(ws + AT_OFF);
  _Float16* Bt = (_Float16*)(ws + BT_OFF);
  _Float16* HP = (_Float16*)(ws + HP_OFF);

  hipMemsetAsync(cnt, 0, NE * sizeof(int), stream);
  hipLaunchKernelGGL(prep_kernel, dim3(1088), dim3(256), 0, stream,
                     ids, A, B, cnt, perm, At, Bt);
  hipLaunchKernelGGL(lora_stage1, dim3(2048), dim3(256), 0, stream,
                     x, At, cnt, perm, HP);
  hipLaunchKernelGGL(lora_stage2, dim3(S2_GRID), dim3(256), 0, stream,
                     baseo, Bt, HP, scaling, cnt, perm, out);
}

// Round 8
// 384.489 us; speedup vs baseline: 1.0860x; 1.0519x over previous
//
#include <hip/hip_runtime.h>

#define TT 16384
#define DD 4096
#define OO 4096
#define NE 8
#define RRK 64

typedef _Float16 f16x8 __attribute__((ext_vector_type(8)));
typedef float f32x4 __attribute__((ext_vector_type(4)));

// workspace layout (bytes)
#define CNT_OFF 0             // 8 ints
#define PERM_OFF 1024         // 8*TT ints = 512KB
#define AT_OFF (1u << 20)     // 8*64*4096 f16 = 4MB: A^T [e][r][k]
#define BT_OFF (5u << 20)     // 8*4096*64 f16 = 4MB: B^T [e][o][r]
#define H_OFF (9u << 20)      // TT*64 f16 = 2MB: H (scaled)

// ---------------------------------------------------------------------------
// prep: scatter tokens into per-adapter buckets; transpose+cast A and B to f16
// ---------------------------------------------------------------------------
__global__ void prep_kernel(const int* __restrict__ ids,
                            const float* __restrict__ A,
                            const float* __restrict__ B,
                            int* __restrict__ cnt,
                            int* __restrict__ perm,
                            _Float16* __restrict__ At,
                            _Float16* __restrict__ Bt) {
  const int bid = blockIdx.x, tid = threadIdx.x;
  if (bid < 64) {                      // scatter
    int t = bid * 256 + tid;
    int e = ids[t];
    int pos = atomicAdd(&cnt[e], 1);
    perm[e * TT + pos] = t;
    return;
  }
  __shared__ float tile[64][65];
  if (bid < 576) {                     // A[e][k][r] -> At[e][r][k]
    int idx = bid - 64;
    int e = idx >> 6, kb = (idx & 63) << 6;
    #pragma unroll
    for (int i = 0; i < 16; ++i) {
      int lin = i * 256 + tid;
      int kr = lin >> 6, r = lin & 63;
      tile[kr][r] = A[((size_t)e * DD + kb + kr) * RRK + r];
    }
    __syncthreads();
    #pragma unroll
    for (int i = 0; i < 16; ++i) {
      int lin = i * 256 + tid;
      int r = lin >> 6, kk = lin & 63;
      At[((size_t)e * RRK + r) * DD + kb + kk] = (_Float16)tile[kk][r];
    }
  } else {                             // B[e][r][o] -> Bt[e][o][r]
    int idx = bid - 576;
    int e = idx >> 6, ob = (idx & 63) << 6;
    #pragma unroll
    for (int i = 0; i < 16; ++i) {
      int lin = i * 256 + tid;
      int r = lin >> 6, o = lin & 63;
      tile[r][o] = B[((size_t)e * RRK + r) * OO + ob + o];
    }
    __syncthreads();
    #pragma unroll
    for (int i = 0; i < 16; ++i) {
      int lin = i * 256 + tid;
      int o = lin >> 6, r2 = lin & 63;
      Bt[((size_t)e * OO + ob + o) * RRK + r2] = (_Float16)tile[r2][o];
    }
  }
}

// ---------------------------------------------------------------------------
// stage 1: H[t][:] = (x[t] @ A[e]) * s_e   — R2-verbatim structure.
// LDS-staged, coalesced; tile 64 tok x 64 R, full K=4096 loop; grid 272.
// ---------------------------------------------------------------------------
__global__ __launch_bounds__(256, 2)
void lora_stage1(const float* __restrict__ x,
                 const _Float16* __restrict__ At,
                 const float* __restrict__ scaling,
                 const int* __restrict__ cnt,
                 const int* __restrict__ perm,
                 _Float16* __restrict__ H) {
  __shared__ _Float16 Xs[64][72];
  __shared__ _Float16 As[64][72];
  __shared__ int toks[64];
  const int tid = threadIdx.x;
  const int lane = tid & 63, w = tid >> 6;

  int tot = 0;
  #pragma unroll
  for (int ee = 0; ee < NE; ++ee) tot += (cnt[ee] + 63) >> 6;

  for (int wi = blockIdx.x; wi < tot; wi += gridDim.x) {
    int e = 0, base = 0, n_e = 0;
    {
      int acc0 = 0;
      #pragma unroll
      for (int ee = 0; ee < NE; ++ee) {
        int c = cnt[ee];
        int tl = (c + 63) >> 6;
        if (wi >= acc0 && wi < acc0 + tl) { e = ee; base = acc0; n_e = c; }
        acc0 += tl;
      }
    }
    int m0 = (wi - base) << 6;

    if (tid < 64) {
      int rloc = m0 + tid;
      toks[tid] = (rloc < n_e) ? perm[e * TT + rloc] : -1;
    }
    __syncthreads();

    const int srow = tid >> 2;           // 0..63: token row (Xs) / r row (As)
    const int seg = (tid & 3) << 4;      // 0,16,32,48: k segment
    int tk0 = toks[srow];
    if (tk0 < 0) tk0 = toks[0];
    const float* xp = x + (size_t)tk0 * DD + seg;
    const _Float16* ap = At + ((size_t)e * RRK + srow) * DD + seg;

    f32x4 acc[4] = {};

    for (int k0 = 0; k0 < DD; k0 += 64) {
      float4 v0 = *(const float4*)(xp + k0);
      float4 v1 = *(const float4*)(xp + k0 + 4);
      float4 v2 = *(const float4*)(xp + k0 + 8);
      float4 v3 = *(const float4*)(xp + k0 + 12);
      f16x8 xa, xb;
      xa[0] = (_Float16)v0.x; xa[1] = (_Float16)v0.y;
      xa[2] = (_Float16)v0.z; xa[3] = (_Float16)v0.w;
      xa[4] = (_Float16)v1.x; xa[5] = (_Float16)v1.y;
      xa[6] = (_Float16)v1.z; xa[7] = (_Float16)v1.w;
      xb[0] = (_Float16)v2.x; xb[1] = (_Float16)v2.y;
      xb[2] = (_Float16)v2.z; xb[3] = (_Float16)v2.w;
      xb[4] = (_Float16)v3.x; xb[5] = (_Float16)v3.y;
      xb[6] = (_Float16)v3.z; xb[7] = (_Float16)v3.w;
      *(f16x8*)&Xs[srow][seg] = xa;
      *(f16x8*)&Xs[srow][seg + 8] = xb;
      *(f16x8*)&As[srow][seg] = *(const f16x8*)(ap + k0);
      *(f16x8*)&As[srow][seg + 8] = *(const f16x8*)(ap + k0 + 8);
      __syncthreads();

      const int mr = w * 16 + (lane & 15);
      const int kq = (lane >> 4) << 3;
      #pragma unroll
      for (int ks = 0; ks < 2; ++ks) {
        f16x8 af = *(const f16x8*)&Xs[mr][ks * 32 + kq];
        #pragma unroll
        for (int nf = 0; nf < 4; ++nf) {
          f16x8 bfr = *(const f16x8*)&As[nf * 16 + (lane & 15)][ks * 32 + kq];
          acc[nf] = __builtin_amdgcn_mfma_f32_16x16x32_f16(af, bfr, acc[nf], 0, 0, 0);
        }
      }
      __syncthreads();
    }

    // epilogue: D layout col=lane&15, row=(lane>>4)*4+reg; fold scaling here
    float s = scaling[e];
    const int rq = (lane >> 4) << 2;
    #pragma unroll
    for (int rg = 0; rg < 4; ++rg) {
      int tk = toks[w * 16 + rq + rg];
      if (tk >= 0) {
        #pragma unroll
        for (int nf = 0; nf < 4; ++nf) {
          H[(size_t)tk * RRK + nf * 16 + (lane & 15)] = (_Float16)(acc[nf][rg] * s);
        }
      }
    }
    __syncthreads();
  }
}

// ---------------------------------------------------------------------------
// stage 2: out[t][:] = base[t][:] + H[t] @ B[e]   (R3 structure, no spill)
// LDS-free, barrier-free, 64 tok x 256 col tiles, 5 blocks/CU.
// Bijective XCD swizzle (grid 4096 = 8*512); M-fastest so the ~tiles_m
// consecutive work items sharing one Bt panel run on the same XCD's L2.
// D = B^T(A-op) x H^T(B-op): lane owns one token row, float4 RMW epilogue.
// ---------------------------------------------------------------------------
#define S2_GRID 4096
__global__ __launch_bounds__(256, 5)
void lora_stage2(const float* __restrict__ baseo,
                 const _Float16* __restrict__ Bt,
                 const _Float16* __restrict__ H,
                 const int* __restrict__ cnt,
                 const int* __restrict__ perm,
                 float* __restrict__ out) {
  const int tid = threadIdx.x;
  const int lane = tid & 63, w = tid >> 6;
  const int lr = lane & 15;
  const int g = lane >> 4;
  const int kq = g << 3;
  const int g4 = g << 2;

  int tot = 0;
  #pragma unroll
  for (int ee = 0; ee < NE; ++ee) tot += ((cnt[ee] + 63) >> 6) << 4;

  // XCD-aware swizzle: consecutive work items -> same XCD
  int bs = ((blockIdx.x & 7) << 9) | (blockIdx.x >> 3);

  for (int wi = bs; wi < tot; wi += S2_GRID) {
    int e = 0, base = 0, n_e = 0;
    {
      int acc0 = 0;
      #pragma unroll
      for (int ee = 0; ee < NE; ++ee) {
        int c = cnt[ee];
        int work = ((c + 63) >> 6) << 4;
        if (wi >= acc0 && wi < acc0 + work) { e = ee; base = acc0; n_e = c; }
        acc0 += work;
      }
    }
    int local = wi - base;
    int tiles_m = (n_e + 63) >> 6;
    int mt = local % tiles_m;           // M fastest: consecutive wi share Bt panel
    int nt = local / tiles_m;
    int m0 = mt << 6, o0 = nt << 8;

    int row = m0 + w * 16 + lr;
    bool valid = row < n_e;
    int tk = perm[e * TT + (valid ? row : n_e - 1)];

    // H fragments (scaling already folded by stage1)
    const _Float16* hp = H + (size_t)tk * RRK + kq;
    f16x8 hf0 = *(const f16x8*)(hp);
    f16x8 hf1 = *(const f16x8*)(hp + 32);

    const _Float16* bp = Bt + ((size_t)e * OO + o0 + lr) * RRK + kq;

    f32x4 acc[16];
    #pragma unroll
    for (int of = 0; of < 16; ++of) acc[of] = (f32x4){0.f, 0.f, 0.f, 0.f};

    #pragma unroll
    for (int of = 0; of < 16; ++of) {
      f16x8 b0 = *(const f16x8*)(bp + (size_t)of * 16 * RRK);
      f16x8 b1 = *(const f16x8*)(bp + (size_t)of * 16 * RRK + 32);
      acc[of] = __builtin_amdgcn_mfma_f32_16x16x32_f16(b0, hf0, acc[of], 0, 0, 0);
      acc[of] = __builtin_amdgcn_mfma_f32_16x16x32_f16(b1, hf1, acc[of], 0, 0, 0);
    }

    if (valid) {
      size_t rowoff = (size_t)tk * OO + o0 + g4;
      #pragma unroll
      for (int of = 0; of < 16; ++of) {
        size_t off = rowoff + (size_t)of * 16;
        float4 b4 = *(const float4*)(baseo + off);
        float4 r4;
        r4.x = b4.x + acc[of][0];
        r4.y = b4.y + acc[of][1];
        r4.z = b4.z + acc[of][2];
        r4.w = b4.w + acc[of][3];
        *(float4*)(out + off) = r4;
      }
    }
  }
}

extern "C" void kernel_launch(void* const* d_in, const int* in_sizes, int n_in,
                              void* d_out, int out_size, void* d_ws, size_t ws_size,
                              hipStream_t stream) {
  const float* x = (const float*)d_in[0];
  const float* baseo = (const float*)d_in[1];
  const float* A = (const float*)d_in[2];
  const float* B = (const float*)d_in[3];
  const float* scaling = (const float*)d_in[4];
  const int* ids = (const int*)d_in[5];
  float* out = (float*)d_out;
  char* ws = (char*)d_ws;

  int* cnt = (int*)(ws + CNT_OFF);
  int* perm = (int*)(ws + PERM_OFF);
  _Float16* At = (_Float16*)(ws + AT_OFF);
  _Float16* Bt = (_Float16*)(ws + BT_OFF);
  _Float16* H = (_Float16*)(ws + H_OFF);

  hipMemsetAsync(cnt, 0, NE * sizeof(int), stream);
  hipLaunchKernelGGL(prep_kernel, dim3(1088), dim3(256), 0, stream,
                     ids, A, B, cnt, perm, At, Bt);
  hipLaunchKernelGGL(lora_stage1, dim3(272), dim3(256), 0, stream,
                     x, At, scaling, cnt, perm, H);
  hipLaunchKernelGGL(lora_stage2, dim3(S2_GRID), dim3(256), 0, stream,
                     baseo, Bt, H, cnt, perm, out);
}

// Round 9
// 325.015 us; speedup vs baseline: 1.2847x; 1.1830x over previous
//
#include <hip/hip_runtime.h>

#define TT 16384
#define DD 4096
#define OO 4096
#define NE 8
#define RRK 64

typedef _Float16 f16x8 __attribute__((ext_vector_type(8)));
typedef float f32x4 __attribute__((ext_vector_type(4)));

// workspace layout (bytes)
#define CNT_OFF 0             // 8 ints
#define PERM_OFF 1024         // 8*TT ints = 512KB
#define AT_OFF (1u << 20)     // 8*64*4096 f16 = 4MB: A^T [e][r][k]
#define BT_OFF (5u << 20)     // 8*4096*64 f16 = 4MB: B^T [e][o][r]
#define H_OFF (9u << 20)      // TT*64 f16 = 2MB: H (scaled)

typedef const __attribute__((address_space(1))) void GPTR;
typedef __attribute__((address_space(3))) void LPTR;
#define GLOAD16(g, l) __builtin_amdgcn_global_load_lds((GPTR*)(g), (LPTR*)(l), 16, 0, 0)

// ---------------------------------------------------------------------------
// prep: scatter tokens into per-adapter buckets; transpose+cast A and B to f16
// ---------------------------------------------------------------------------
__global__ void prep_kernel(const int* __restrict__ ids,
                            const float* __restrict__ A,
                            const float* __restrict__ B,
                            int* __restrict__ cnt,
                            int* __restrict__ perm,
                            _Float16* __restrict__ At,
                            _Float16* __restrict__ Bt) {
  const int bid = blockIdx.x, tid = threadIdx.x;
  if (bid < 64) {                      // scatter
    int t = bid * 256 + tid;
    int e = ids[t];
    int pos = atomicAdd(&cnt[e], 1);
    perm[e * TT + pos] = t;
    return;
  }
  __shared__ float tile[64][65];
  if (bid < 576) {                     // A[e][k][r] -> At[e][r][k]
    int idx = bid - 64;
    int e = idx >> 6, kb = (idx & 63) << 6;
    #pragma unroll
    for (int i = 0; i < 16; ++i) {
      int lin = i * 256 + tid;
      int kr = lin >> 6, r = lin & 63;
      tile[kr][r] = A[((size_t)e * DD + kb + kr) * RRK + r];
    }
    __syncthreads();
    #pragma unroll
    for (int i = 0; i < 16; ++i) {
      int lin = i * 256 + tid;
      int r = lin >> 6, kk = lin & 63;
      At[((size_t)e * RRK + r) * DD + kb + kk] = (_Float16)tile[kk][r];
    }
  } else {                             // B[e][r][o] -> Bt[e][o][r]
    int idx = bid - 576;
    int e = idx >> 6, ob = (idx & 63) << 6;
    #pragma unroll
    for (int i = 0; i < 16; ++i) {
      int lin = i * 256 + tid;
      int r = lin >> 6, o = lin & 63;
      tile[r][o] = B[((size_t)e * RRK + r) * OO + ob + o];
    }
    __syncthreads();
    #pragma unroll
    for (int i = 0; i < 16; ++i) {
      int lin = i * 256 + tid;
      int o = lin >> 6, r2 = lin & 63;
      Bt[((size_t)e * OO + ob + o) * RRK + r2] = (_Float16)tile[r2][o];
    }
  }
}

// ---------------------------------------------------------------------------
// stage 1: H[t][:] = (x[t] @ A[e]) * s_e
// T3 minimum-2-phase: double-buffered LDS, global_load_lds(16B) staging of
// x (f32) + At (f16), ONE barrier per K-step, prefetch issued before compute.
// Both-sides 16B-granule XOR swizzle (gr ^= row&7) for conflict-free ds_reads
// with a linear global_load_lds destination (rule #21).
// Tile 64 tok x 64 R, K-step 64. LDS 48KB.
// ---------------------------------------------------------------------------
#define S1_GRID 320
__global__ __launch_bounds__(256, 2)
void lora_stage1(const float* __restrict__ x,
                 const _Float16* __restrict__ At,
                 const float* __restrict__ scaling,
                 const int* __restrict__ cnt,
                 const int* __restrict__ perm,
                 _Float16* __restrict__ H) {
  __shared__ float Xs[2][4096];      // [64 rows][16 granules of 4 f32], swizzled
  __shared__ _Float16 As[2][4096];   // [64 rows][8 granules of 8 f16], swizzled
  __shared__ int toks[64];
  __shared__ int tokc[64];
  const int tid = threadIdx.x;
  const int lane = tid & 63, w = tid >> 6;
  const int lr = lane & 15, g = lane >> 4;
  const int s = lr & 7;
  const int mr = w * 16 + lr;

  // staging source granule swizzles (p-independent)
  const int sgx = (tid & 15) ^ ((tid >> 4) & 7);
  const int sga = (tid & 7) ^ ((tid >> 3) & 7);

  int tiles = 0;
  #pragma unroll
  for (int ee = 0; ee < NE; ++ee) tiles += (cnt[ee] + 63) >> 6;

  for (int wi = blockIdx.x; wi < tiles; wi += S1_GRID) {
    int e = 0, base = 0, n_e = 0;
    {
      int acc0 = 0;
      #pragma unroll
      for (int ee = 0; ee < NE; ++ee) {
        int c = cnt[ee];
        int tl = (c + 63) >> 6;
        if (wi >= acc0 && wi < acc0 + tl) { e = ee; base = acc0; n_e = c; }
        acc0 += tl;
      }
    }
    int m0 = (wi - base) << 6;

    if (tid < 64) {
      int rloc = m0 + tid;
      int v = (rloc < n_e) ? perm[e * TT + rloc] : -1;
      toks[tid] = v;
      tokc[tid] = (v < 0) ? perm[e * TT + n_e - 1] : v;
    }
    __syncthreads();

    // per-thread staging tokens / output tokens -> registers
    const float* xsrc[4];
    #pragma unroll
    for (int p = 0; p < 4; ++p)
      xsrc[p] = x + (size_t)tokc[p * 16 + (tid >> 4)] * DD + sgx * 4;
    const _Float16* asrc = At + ((size_t)e * RRK + (tid >> 3)) * DD + sga * 8;
    int otok[4];
    #pragma unroll
    for (int rg = 0; rg < 4; ++rg) otok[rg] = toks[w * 16 + g * 4 + rg];

    f32x4 acc[4] = {};

    // prologue stage
    #pragma unroll
    for (int p = 0; p < 4; ++p)
      GLOAD16(xsrc[p], (char*)Xs[0] + p * 4096 + tid * 16);
    #pragma unroll
    for (int p = 0; p < 2; ++p)
      GLOAD16(asrc + (size_t)p * 32 * DD, (char*)As[0] + p * 4096 + tid * 16);
    __syncthreads();

    for (int it = 0; it < 64; ++it) {
      int cur = it & 1;
      int kb = (it + 1) << 6;
      if (it < 63) {                    // prefetch next K-step into other buffer
        #pragma unroll
        for (int p = 0; p < 4; ++p)
          GLOAD16(xsrc[p] + kb, (char*)Xs[cur ^ 1] + p * 4096 + tid * 16);
        #pragma unroll
        for (int p = 0; p < 2; ++p)
          GLOAD16(asrc + (size_t)p * 32 * DD + kb, (char*)As[cur ^ 1] + p * 4096 + tid * 16);
      }

      const f32x4* xr = (const f32x4*)Xs[cur];   // 16 granules per row
      const f16x8* ar = (const f16x8*)As[cur];   // 8 granules per row
      #pragma unroll
      for (int ks = 0; ks < 2; ++ks) {
        f32x4 a0 = xr[mr * 16 + ((2 * g + 8 * ks) ^ s)];
        f32x4 a1 = xr[mr * 16 + ((2 * g + 8 * ks + 1) ^ s)];
        f16x8 xa;
        #pragma unroll
        for (int i = 0; i < 4; ++i) {
          xa[i] = (_Float16)a0[i];
          xa[4 + i] = (_Float16)a1[i];
        }
        #pragma unroll
        for (int nf = 0; nf < 4; ++nf) {
          f16x8 bfr = ar[(nf * 16 + lr) * 8 + ((g + 4 * ks) ^ s)];
          acc[nf] = __builtin_amdgcn_mfma_f32_16x16x32_f16(xa, bfr, acc[nf], 0, 0, 0);
        }
      }
      __syncthreads();                  // drains prefetch + protects buffers
    }

    // epilogue: D rows = tokens (g*4+reg), cols = r (nf*16+lr); fold scaling
    float sc = scaling[e];
    #pragma unroll
    for (int rg = 0; rg < 4; ++rg) {
      int tk = otok[rg];
      if (tk >= 0) {
        #pragma unroll
        for (int nf = 0; nf < 4; ++nf) {
          H[(size_t)tk * RRK + nf * 16 + lr] = (_Float16)(acc[nf][rg] * sc);
        }
      }
    }
  }
}

// ---------------------------------------------------------------------------
// stage 2: out[t][:] = base[t][:] + H[t] @ B[e]   (R3-exact + batched epilogue)
// LDS-free, barrier-free, 64 tok x 256 col tiles, bounds(256,4), grid 4096.
// Epilogue groups 8 base-loads then 8 stores to cut DRAM read/write turnaround.
// D = B^T(A-op) x H^T(B-op): lane owns one token row, float4 RMW epilogue.
// ---------------------------------------------------------------------------
#define S2_GRID 4096
__global__ __launch_bounds__(256, 4)
void lora_stage2(const float* __restrict__ baseo,
                 const _Float16* __restrict__ Bt,
                 const _Float16* __restrict__ H,
                 const int* __restrict__ cnt,
                 const int* __restrict__ perm,
                 float* __restrict__ out) {
  const int tid = threadIdx.x;
  const int lane = tid & 63, w = tid >> 6;
  const int lr = lane & 15;
  const int g = lane >> 4;
  const int kq = g << 3;
  const int g4 = g << 2;

  int tot = 0;
  #pragma unroll
  for (int ee = 0; ee < NE; ++ee) tot += ((cnt[ee] + 63) >> 6) << 4;

  for (int wi = blockIdx.x; wi < tot; wi += S2_GRID) {
    int e = 0, base = 0, n_e = 0;
    {
      int acc0 = 0;
      #pragma unroll
      for (int ee = 0; ee < NE; ++ee) {
        int c = cnt[ee];
        int work = ((c + 63) >> 6) << 4;
        if (wi >= acc0 && wi < acc0 + work) { e = ee; base = acc0; n_e = c; }
        acc0 += work;
      }
    }
    int local = wi - base;
    int tiles_m = (n_e + 63) >> 6;
    int mt = local % tiles_m;           // M fastest: consecutive wi share Bt panel
    int nt = local / tiles_m;
    int m0 = mt << 6, o0 = nt << 8;

    int row = m0 + w * 16 + lr;
    bool valid = row < n_e;
    int tk = perm[e * TT + (valid ? row : n_e - 1)];

    // H fragments (scaling already folded by stage1)
    const _Float16* hp = H + (size_t)tk * RRK + kq;
    f16x8 hf0 = *(const f16x8*)(hp);
    f16x8 hf1 = *(const f16x8*)(hp + 32);

    const _Float16* bp = Bt + ((size_t)e * OO + o0 + lr) * RRK + kq;

    f32x4 acc[16];
    #pragma unroll
    for (int of = 0; of < 16; ++of) acc[of] = (f32x4){0.f, 0.f, 0.f, 0.f};

    #pragma unroll
    for (int of = 0; of < 16; ++of) {
      f16x8 b0 = *(const f16x8*)(bp + (size_t)of * 16 * RRK);
      f16x8 b1 = *(const f16x8*)(bp + (size_t)of * 16 * RRK + 32);
      acc[of] = __builtin_amdgcn_mfma_f32_16x16x32_f16(b0, hf0, acc[of], 0, 0, 0);
      acc[of] = __builtin_amdgcn_mfma_f32_16x16x32_f16(b1, hf1, acc[of], 0, 0, 0);
    }

    if (valid) {
      size_t rowoff = (size_t)tk * OO + o0 + g4;
      #pragma unroll
      for (int h = 0; h < 2; ++h) {
        float4 bv[8];
        #pragma unroll
        for (int j = 0; j < 8; ++j)
          bv[j] = *(const float4*)(baseo + rowoff + (size_t)(h * 8 + j) * 16);
        #pragma unroll
        for (int j = 0; j < 8; ++j) {
          int of = h * 8 + j;
          float4 r4;
          r4.x = bv[j].x + acc[of][0];
          r4.y = bv[j].y + acc[of][1];
          r4.z = bv[j].z + acc[of][2];
          r4.w = bv[j].w + acc[of][3];
          *(float4*)(out + rowoff + (size_t)of * 16) = r4;
        }
      }
    }
  }
}

extern "C" void kernel_launch(void* const* d_in, const int* in_sizes, int n_in,
                              void* d_out, int out_size, void* d_ws, size_t ws_size,
                              hipStream_t stream) {
  const float* x = (const float*)d_in[0];
  const float* baseo = (const float*)d_in[1];
  const float* A = (const float*)d_in[2];
  const float* B = (const float*)d_in[3];
  const float* scaling = (const float*)d_in[4];
  const int* ids = (const int*)d_in[5];
  float* out = (float*)d_out;
  char* ws = (char*)d_ws;

  int* cnt = (int*)(ws + CNT_OFF);
  int* perm = (int*)(ws + PERM_OFF);
  _Float16* At = (_Float16*)(ws + AT_OFF);
  _Float16* Bt = (_Float16*)(ws + BT_OFF);
  _Float16* H = (_Float16*)(ws + H_OFF);

  hipMemsetAsync(cnt, 0, NE * sizeof(int), stream);
  hipLaunchKernelGGL(prep_kernel, dim3(1088), dim3(256), 0, stream,
                     ids, A, B, cnt, perm, At, Bt);
  hipLaunchKernelGGL(lora_stage1, dim3(S1_GRID), dim3(256), 0, stream,
                     x, At, scaling, cnt, perm, H);
  hipLaunchKernelGGL(lora_stage2, dim3(S2_GRID), dim3(256), 0, stream,
                     baseo, Bt, H, cnt, perm, out);
}

// Round 10
// 304.254 us; speedup vs baseline: 1.3724x; 1.0682x over previous
//
#include <hip/hip_runtime.h>

#define TT 16384
#define DD 4096
#define OO 4096
#define NE 8
#define RRK 64

typedef _Float16 f16x8 __attribute__((ext_vector_type(8)));
typedef _Float16 f16x4 __attribute__((ext_vector_type(4)));
typedef float f32x4 __attribute__((ext_vector_type(4)));

// workspace layout (bytes)
#define CNT_OFF 0             // 8 ints
#define PERM_OFF 1024         // 8*TT ints = 512KB
#define AT_OFF (1u << 20)     // 8*64*4096 f16 = 4MB: A^T [e][r][k]
#define BT_OFF (5u << 20)     // 8*4096*64 f16 = 4MB: B^T [e][o][r]
#define H_OFF (9u << 20)      // TT*64 f16 = 2MB: H (scaled)

typedef const __attribute__((address_space(1))) void GPTR;
typedef __attribute__((address_space(3))) void LPTR;
#define GLOAD16(g, l) __builtin_amdgcn_global_load_lds((GPTR*)(g), (LPTR*)(l), 16, 0, 0)

// ---------------------------------------------------------------------------
// prep: scatter tokens into per-adapter buckets (LDS histogram, 8 global
// atomics per block) + transpose+cast A and B to f16
// ---------------------------------------------------------------------------
__global__ void prep_kernel(const int* __restrict__ ids,
                            const float* __restrict__ A,
                            const float* __restrict__ B,
                            int* __restrict__ cnt,
                            int* __restrict__ perm,
                            _Float16* __restrict__ At,
                            _Float16* __restrict__ Bt) {
  const int bid = blockIdx.x, tid = threadIdx.x;
  if (bid < 64) {                      // scatter via block-local histogram
    __shared__ int h1[NE], h2[NE], bases[NE];
    if (tid < NE) { h1[tid] = 0; h2[tid] = 0; }
    __syncthreads();
    int t = bid * 256 + tid;
    int e = ids[t];
    atomicAdd(&h1[e], 1);              // LDS atomic
    __syncthreads();
    if (tid < NE) bases[tid] = atomicAdd(&cnt[tid], h1[tid]);   // 8 global atomics
    __syncthreads();
    int pos = bases[e] + atomicAdd(&h2[e], 1);                  // LDS atomic
    perm[e * TT + pos] = t;
    return;
  }
  __shared__ float tile[64][65];
  if (bid < 576) {                     // A[e][k][r] -> At[e][r][k]
    int idx = bid - 64;
    int e = idx >> 6, kb = (idx & 63) << 6;
    #pragma unroll
    for (int i = 0; i < 16; ++i) {
      int lin = i * 256 + tid;
      int kr = lin >> 6, r = lin & 63;
      tile[kr][r] = A[((size_t)e * DD + kb + kr) * RRK + r];
    }
    __syncthreads();
    #pragma unroll
    for (int i = 0; i < 16; ++i) {
      int lin = i * 256 + tid;
      int r = lin >> 6, kk = lin & 63;
      At[((size_t)e * RRK + r) * DD + kb + kk] = (_Float16)tile[kk][r];
    }
  } else {                             // B[e][r][o] -> Bt[e][o][r]
    int idx = bid - 576;
    int e = idx >> 6, ob = (idx & 63) << 6;
    #pragma unroll
    for (int i = 0; i < 16; ++i) {
      int lin = i * 256 + tid;
      int r = lin >> 6, o = lin & 63;
      tile[r][o] = B[((size_t)e * RRK + r) * OO + ob + o];
    }
    __syncthreads();
    #pragma unroll
    for (int i = 0; i < 16; ++i) {
      int lin = i * 256 + tid;
      int o = lin >> 6, r2 = lin & 63;
      Bt[((size_t)e * OO + ob + o) * RRK + r2] = (_Float16)tile[r2][o];
    }
  }
}

// ---------------------------------------------------------------------------
// stage 1: H[t][:] = (x[t] @ A[e]) * s_e
// 16-token tiles (>=1024 work items -> 4 blocks/CU). LDS 20KB:
//   As[2][64r][64k] f16 via global_load_lds(16B), source pre-swizzled
//   Xs[2][16t][64k] f16 reg-staged f32->f16, granule16 XOR-swizzled
// One barrier per K-step; prefetch issued before compute. Wave w owns
// R-columns w*16..w*16+15 (B-fragment rows), acc = one f32x4 per lane.
// ---------------------------------------------------------------------------
#define S1_GRID 1024
__global__ __launch_bounds__(256, 4)
void lora_stage1(const float* __restrict__ x,
                 const _Float16* __restrict__ At,
                 const float* __restrict__ scaling,
                 const int* __restrict__ cnt,
                 const int* __restrict__ perm,
                 _Float16* __restrict__ H) {
  __shared__ _Float16 As[2][4096];   // 64 rows x 8 granules(16B), swizzled
  __shared__ _Float16 Xs[2][1024];   // 16 rows x 8 granules(16B), swizzled
  __shared__ int toks[16];
  const int tid = threadIdx.x;
  const int lane = tid & 63, w = tid >> 6;
  const int lr = lane & 15, g = lane >> 4;

  // As staging source: dest granule G=p*256+tid -> row G>>3, slot G&7,
  // source granule = slot ^ (row&7)  (row&7 invariant under +32)
  const int arow = tid >> 3;
  const int agr = (tid & 7) ^ ((tid >> 3) & 7);
  // Xs staging: thread covers row tid>>4, k-seg (tid&15)*4 (one float4)
  const int xrow = tid >> 4;
  const int xbyte = xrow * 128 + ((((tid & 15) >> 1) ^ (xrow & 7)) << 4) + ((tid & 1) << 3);
  // fragment read offsets (row&7 == lr&7 for both Xs and As)
  const int fr_sw = lr & 7;

  int tiles = 0;
  #pragma unroll
  for (int ee = 0; ee < NE; ++ee) tiles += (cnt[ee] + 15) >> 4;

  for (int wi = blockIdx.x; wi < tiles; wi += S1_GRID) {
    int e = 0, base = 0, n_e = 0;
    {
      int acc0 = 0;
      #pragma unroll
      for (int ee = 0; ee < NE; ++ee) {
        int c = cnt[ee];
        int tl = (c + 15) >> 4;
        if (wi >= acc0 && wi < acc0 + tl) { e = ee; base = acc0; n_e = c; }
        acc0 += tl;
      }
    }
    int m0 = (wi - base) << 4;

    if (tid < 16) {
      int rloc = m0 + tid;
      toks[tid] = (rloc < n_e) ? perm[e * TT + rloc] : -1;
    }
    __syncthreads();

    int stok = toks[xrow];
    if (stok < 0) stok = toks[0];      // row 0 of an existing tile is valid
    const float* xsrc = x + (size_t)stok * DD + ((tid & 15) << 2);
    const _Float16* asrc = At + ((size_t)e * RRK + arow) * DD + agr * 8;

    f32x4 acc = {};

    // prologue: stage k-step 0
    {
      float4 v = *(const float4*)(xsrc);
      GLOAD16(asrc, (char*)As[0] + tid * 16);
      GLOAD16(asrc + (size_t)32 * DD, (char*)As[0] + 4096 + tid * 16);
      f16x4 cv;
      cv[0] = (_Float16)v.x; cv[1] = (_Float16)v.y;
      cv[2] = (_Float16)v.z; cv[3] = (_Float16)v.w;
      *(f16x4*)((char*)Xs[0] + xbyte) = cv;
    }
    __syncthreads();

    for (int it = 0; it < 64; ++it) {
      int cur = it & 1;
      float4 vn;
      if (it < 63) {                   // issue next-step loads before compute
        int kb = (it + 1) << 6;
        vn = *(const float4*)(xsrc + kb);
        GLOAD16(asrc + kb, (char*)As[cur ^ 1] + tid * 16);
        GLOAD16(asrc + (size_t)32 * DD + kb, (char*)As[cur ^ 1] + 4096 + tid * 16);
      }

      #pragma unroll
      for (int ks = 0; ks < 2; ++ks) {
        int gr = (4 * ks + g) ^ fr_sw;
        f16x8 xa = *(const f16x8*)((char*)Xs[cur] + lr * 128 + gr * 16);
        f16x8 bf = *(const f16x8*)((char*)As[cur] + (w * 16 + lr) * 128 + gr * 16);
        acc = __builtin_amdgcn_mfma_f32_16x16x32_f16(xa, bf, acc, 0, 0, 0);
      }

      if (it < 63) {                   // write next Xs after current reads
        f16x4 cv;
        cv[0] = (_Float16)vn.x; cv[1] = (_Float16)vn.y;
        cv[2] = (_Float16)vn.z; cv[3] = (_Float16)vn.w;
        *(f16x4*)((char*)Xs[cur ^ 1] + xbyte) = cv;
      }
      __syncthreads();
    }

    // epilogue: D rows = tokens g*4+rg, col = w*16+lr; fold scaling
    float sc = scaling[e];
    #pragma unroll
    for (int rg = 0; rg < 4; ++rg) {
      int tk = toks[g * 4 + rg];
      if (tk >= 0)
        H[(size_t)tk * RRK + w * 16 + lr] = (_Float16)(acc[rg] * sc);
    }
    __syncthreads();
  }
}

// ---------------------------------------------------------------------------
// stage 2: out[t][:] = base[t][:] + H[t] @ B[e]   (R9-exact, measured 162us)
// LDS-free, barrier-free, 64 tok x 256 col tiles, bounds(256,4), grid 4096.
// D = B^T(A-op) x H^T(B-op): lane owns one token row, float4 RMW epilogue.
// ---------------------------------------------------------------------------
#define S2_GRID 4096
__global__ __launch_bounds__(256, 4)
void lora_stage2(const float* __restrict__ baseo,
                 const _Float16* __restrict__ Bt,
                 const _Float16* __restrict__ H,
                 const int* __restrict__ cnt,
                 const int* __restrict__ perm,
                 float* __restrict__ out) {
  const int tid = threadIdx.x;
  const int lane = tid & 63, w = tid >> 6;
  const int lr = lane & 15;
  const int g = lane >> 4;
  const int kq = g << 3;
  const int g4 = g << 2;

  int tot = 0;
  #pragma unroll
  for (int ee = 0; ee < NE; ++ee) tot += ((cnt[ee] + 63) >> 6) << 4;

  for (int wi = blockIdx.x; wi < tot; wi += S2_GRID) {
    int e = 0, base = 0, n_e = 0;
    {
      int acc0 = 0;
      #pragma unroll
      for (int ee = 0; ee < NE; ++ee) {
        int c = cnt[ee];
        int work = ((c + 63) >> 6) << 4;
        if (wi >= acc0 && wi < acc0 + work) { e = ee; base = acc0; n_e = c; }
        acc0 += work;
      }
    }
    int local = wi - base;
    int tiles_m = (n_e + 63) >> 6;
    int mt = local % tiles_m;           // M fastest: consecutive wi share Bt panel
    int nt = local / tiles_m;
    int m0 = mt << 6, o0 = nt << 8;

    int row = m0 + w * 16 + lr;
    bool valid = row < n_e;
    int tk = perm[e * TT + (valid ? row : n_e - 1)];

    // H fragments (scaling already folded by stage1)
    const _Float16* hp = H + (size_t)tk * RRK + kq;
    f16x8 hf0 = *(const f16x8*)(hp);
    f16x8 hf1 = *(const f16x8*)(hp + 32);

    const _Float16* bp = Bt + ((size_t)e * OO + o0 + lr) * RRK + kq;

    f32x4 acc[16];
    #pragma unroll
    for (int of = 0; of < 16; ++of) acc[of] = (f32x4){0.f, 0.f, 0.f, 0.f};

    #pragma unroll
    for (int of = 0; of < 16; ++of) {
      f16x8 b0 = *(const f16x8*)(bp + (size_t)of * 16 * RRK);
      f16x8 b1 = *(const f16x8*)(bp + (size_t)of * 16 * RRK + 32);
      acc[of] = __builtin_amdgcn_mfma_f32_16x16x32_f16(b0, hf0, acc[of], 0, 0, 0);
      acc[of] = __builtin_amdgcn_mfma_f32_16x16x32_f16(b1, hf1, acc[of], 0, 0, 0);
    }

    if (valid) {
      size_t rowoff = (size_t)tk * OO + o0 + g4;
      #pragma unroll
      for (int h = 0; h < 2; ++h) {
        float4 bv[8];
        #pragma unroll
        for (int j = 0; j < 8; ++j)
          bv[j] = *(const float4*)(baseo + rowoff + (size_t)(h * 8 + j) * 16);
        #pragma unroll
        for (int j = 0; j < 8; ++j) {
          int of = h * 8 + j;
          float4 r4;
          r4.x = bv[j].x + acc[of][0];
          r4.y = bv[j].y + acc[of][1];
          r4.z = bv[j].z + acc[of][2];
          r4.w = bv[j].w + acc[of][3];
          *(float4*)(out + rowoff + (size_t)of * 16) = r4;
        }
      }
    }
  }
}

extern "C" void kernel_launch(void* const* d_in, const int* in_sizes, int n_in,
                              void* d_out, int out_size, void* d_ws, size_t ws_size,
                              hipStream_t stream) {
  const float* x = (const float*)d_in[0];
  const float* baseo = (const float*)d_in[1];
  const float* A = (const float*)d_in[2];
  const float* B = (const float*)d_in[3];
  const float* scaling = (const float*)d_in[4];
  const int* ids = (const int*)d_in[5];
  float* out = (float*)d_out;
  char* ws = (char*)d_ws;

  int* cnt = (int*)(ws + CNT_OFF);
  int* perm = (int*)(ws + PERM_OFF);
  _Float16* At = (_Float16*)(ws + AT_OFF);
  _Float16* Bt = (_Float16*)(ws + BT_OFF);
  _Float16* H = (_Float16*)(ws + H_OFF);

  hipMemsetAsync(cnt, 0, NE * sizeof(int), stream);
  hipLaunchKernelGGL(prep_kernel, dim3(1088), dim3(256), 0, stream,
                     ids, A, B, cnt, perm, At, Bt);
  hipLaunchKernelGGL(lora_stage1, dim3(S1_GRID), dim3(256), 0, stream,
                     x, At, scaling, cnt, perm, H);
  hipLaunchKernelGGL(lora_stage2, dim3(S2_GRID), dim3(256), 0, stream,
                     baseo, Bt, H, cnt, perm, out);
}